// Round 1
// baseline (767.912 us; speedup 1.0000x reference)
//
#include <hip/hip_runtime.h>
#include <cmath>

#ifndef __has_builtin
#define __has_builtin(x) 0
#endif

#define B_DIM 4096
#define K_DIM 2048
#define N_DIM 2048

#define BM 128
#define BN 128
#define BK 64

typedef __attribute__((ext_vector_type(4))) float f32x4;
typedef __attribute__((ext_vector_type(8))) short bf16x8;
typedef __attribute__((ext_vector_type(8))) unsigned short u16x8;

// ---------- helpers ----------

__device__ __forceinline__ unsigned short f2bf(float f) {
    unsigned int u = __float_as_uint(f);
    u += 0x7fffu + ((u >> 16) & 1u);   // RNE; inputs here are small exact ints, no NaN
    return (unsigned short)(u >> 16);
}

__device__ __forceinline__ void gl2lds16(const void* g, void* l) {
#if __has_builtin(__builtin_amdgcn_global_load_lds)
    __builtin_amdgcn_global_load_lds((__attribute__((address_space(1))) void*)g,
                                     (__attribute__((address_space(3))) void*)l,
                                     16, 0, 0);
#else
    *(uint4*)l = *(const uint4*)g;
#endif
}

// ---------- prep: fp32 -> bf16 casts ----------

__global__ void cast_x_kernel(const float* __restrict__ X,
                              unsigned short* __restrict__ Xb) {
    size_t i = ((size_t)blockIdx.x * 256 + threadIdx.x) * 8;
    f32x4 a = *(const f32x4*)(X + i);
    f32x4 b = *(const f32x4*)(X + i + 4);
    u16x8 o;
    o[0] = f2bf(a[0]); o[1] = f2bf(a[1]); o[2] = f2bf(a[2]); o[3] = f2bf(a[3]);
    o[4] = f2bf(b[0]); o[5] = f2bf(b[1]); o[6] = f2bf(b[2]); o[7] = f2bf(b[3]);
    *(u16x8*)(Xb + i) = o;
}

__global__ void cast_w_kernel(const float* __restrict__ Wa,
                              const float* __restrict__ Ws,
                              unsigned short* __restrict__ Wab,
                              unsigned short* __restrict__ Wsb) {
    size_t i = ((size_t)blockIdx.x * 256 + threadIdx.x) * 8;
    f32x4 a0 = *(const f32x4*)(Wa + i);
    f32x4 a1 = *(const f32x4*)(Wa + i + 4);
    f32x4 s0 = *(const f32x4*)(Ws + i);
    f32x4 s1 = *(const f32x4*)(Ws + i + 4);
    u16x8 oa, os;
#pragma unroll
    for (int j = 0; j < 4; j++) {
        oa[j]     = f2bf(rintf(a0[j]));  // ste_round fwd = round-half-even
        oa[j + 4] = f2bf(rintf(a1[j]));
        os[j]     = f2bf(rintf(s0[j]));
        os[j + 4] = f2bf(rintf(s1[j]));
    }
    *(u16x8*)(Wab + i) = oa;
    *(u16x8*)(Wsb + i) = os;
}

// ---------- fused dual-GEMM + DPI neuron update ----------
// C_a[b,o] = sum_k X[b,k] * Wa[o,k];  C_s likewise (NT GEMM, both row-major along K)
// 128x128 tile, BK=64, 4 waves in 2x2, each wave 64x64 via 4x4 mfma_f32_16x16x32_bf16
// per-GEMM; epilogue applies the neuron dynamics and writes 5 output planes.

__global__ __launch_bounds__(256, 2)
void dpi_fused_kernel(const unsigned short* __restrict__ Xb,
                      const unsigned short* __restrict__ Wab,
                      const unsigned short* __restrict__ Wsb,
                      const float* __restrict__ gImem,
                      const float* __restrict__ gIampa,
                      const float* __restrict__ gIshunt,
                      const float* __restrict__ gRefr,
                      const float* __restrict__ pIdc,
                      const float* __restrict__ pIwa,
                      const float* __restrict__ pIws,
                      const float* __restrict__ pAlpha,
                      const float* __restrict__ pBeta,
                      float* __restrict__ out,
                      float i0pow, float kexp, float tau_mem, float tau_syn)
{
    __shared__ __align__(16) unsigned short sA [BM * BK];
    __shared__ __align__(16) unsigned short sWa[BN * BK];
    __shared__ __align__(16) unsigned short sWs[BN * BK];

    const int tid  = threadIdx.x;
    const int lane = tid & 63;
    const int wave = tid >> 6;
    const int m0 = blockIdx.x * BM;
    const int n0 = blockIdx.y * BN;
    const int wm = (wave & 1) * 64;
    const int wn = (wave >> 1) * 64;

    f32x4 accA[4][4], accS[4][4];
#pragma unroll
    for (int i = 0; i < 4; i++)
#pragma unroll
        for (int j = 0; j < 4; j++) { accA[i][j] = (f32x4)0.0f; accS[i][j] = (f32x4)0.0f; }

    const int frow = lane & 15;           // m (or n) within a 16-frag
    const int fk   = (lane >> 4) * 8;     // k sub-offset within 32

    for (int k0 = 0; k0 < K_DIM; k0 += BK) {
        // stage 3 tiles: each 128x64 bf16 = 16KB = 1024 x 16B chunks; 256 thr x 4
#pragma unroll
        for (int j = 0; j < 4; j++) {
            int c   = j * 256 + tid;      // wave-contiguous: lds dst = base + lane*16
            int row = c >> 3;
            int cc  = c & 7;
            size_t goffA = (size_t)(m0 + row) * K_DIM + k0 + cc * 8;
            size_t goffW = (size_t)(n0 + row) * K_DIM + k0 + cc * 8;
            gl2lds16(Xb  + goffA, sA  + c * 8);
            gl2lds16(Wab + goffW, sWa + c * 8);
            gl2lds16(Wsb + goffW, sWs + c * 8);
        }
        __syncthreads();

#pragma unroll
        for (int kk = 0; kk < 2; kk++) {
            const int ko = kk * 32 + fk;
            bf16x8 af[4], ba[4], bs[4];
#pragma unroll
            for (int mi = 0; mi < 4; mi++)
                af[mi] = *(const bf16x8*)(sA + (wm + mi * 16 + frow) * BK + ko);
#pragma unroll
            for (int ni = 0; ni < 4; ni++) {
                ba[ni] = *(const bf16x8*)(sWa + (wn + ni * 16 + frow) * BK + ko);
                bs[ni] = *(const bf16x8*)(sWs + (wn + ni * 16 + frow) * BK + ko);
            }
#pragma unroll
            for (int mi = 0; mi < 4; mi++)
#pragma unroll
                for (int ni = 0; ni < 4; ni++) {
                    accA[mi][ni] = __builtin_amdgcn_mfma_f32_16x16x32_bf16(af[mi], ba[ni], accA[mi][ni], 0, 0, 0);
                    accS[mi][ni] = __builtin_amdgcn_mfma_f32_16x16x32_bf16(af[mi], bs[ni], accS[mi][ni], 0, 0, 0);
                }
        }
        __syncthreads();
    }

    // ---- epilogue: DPI neuron update ----
    const float idc   = *pIdc;
    const float iwa   = *pIwa;
    const float iws   = *pIws;
    const float alpha = *pAlpha;
    const float beta  = *pBeta;

    const size_t plane = (size_t)B_DIM * N_DIM;
    float* __restrict__ oSpike = out;
    float* __restrict__ oImem  = out + plane;
    float* __restrict__ oIampa = out + 2 * plane;
    float* __restrict__ oIsh   = out + 3 * plane;
    float* __restrict__ oRefr  = out + 4 * plane;

    // C/D layout: col = lane&15, row = (lane>>4)*4 + reg
    const int colb = n0 + wn + (lane & 15);
    const int rowb = m0 + wm + ((lane >> 4) << 2);

#pragma unroll
    for (int mi = 0; mi < 4; mi++) {
#pragma unroll
        for (int ni = 0; ni < 4; ni++) {
            const int col = colb + ni * 16;
#pragma unroll
            for (int r = 0; r < 4; r++) {
                const int row = rowb + mi * 16 + r;
                const size_t idx = (size_t)row * N_DIM + col;
                const float na = accA[mi][ni][r];
                const float ns = accS[mi][ni][r];

                const float im  = gImem[idx];
                const float ia  = gIampa[idx];
                const float ish = gIshunt[idx];
                const float rf  = gRefr[idx];

                const float dIampa  = -ia / tau_syn;           // TAU_AMPA
                const float ia2     = ia + iwa * na;           // IGAIN_AMPA/ITAU_AMPA = 1
                const float dIshunt = -ish / tau_syn;          // TAU_SHUNT == TAU_AMPA
                const float ish2    = ish + iws * ns;

                float Iin = idc + ia2 + 5e-13f - ish2;         // Inmda = I0
                Iin = (rf <= 0.0f) ? Iin : 0.0f;
                Iin = fmaxf(Iin, 5e-13f);

                const float ifb = i0pow * powf(im, kexp)
                                  / (1.0f + expf(-1e-12f * (im - 1e-12f)));
                const float fimem = ifb / 1e-12f * (im + 1e-12f);
                const float dImem = (alpha * (Iin - 1e-12f - 5e-13f) - beta * im + fimem)
                                    / (tau_mem * (1.0f + 1e-12f / im));
                float im2 = fmaxf(im + dImem * 0.001f, 5e-13f);

                float ia3 = fmaxf(ia2 + dIampa * 0.001f, 5e-13f);
                ia3       = fmaxf(ia3 + dIshunt * 0.001f, 5e-13f);  // faithful to ref bug

                const float spike = (im2 - 1e-12f > 0.0f) ? 1.0f : 0.0f;
                im2 = (1.0f - spike) * im2 + spike * 5e-13f;
                float rf2 = fmaxf(rf - 0.001f, 0.0f);
                rf2 = (1.0f - spike) * rf2;                    // REFP = 0

                oSpike[idx] = spike;
                oImem[idx]  = im2;
                oIampa[idx] = ia3;
                oIsh[idx]   = ish2;
                oRefr[idx]  = rf2;
            }
        }
    }
}

// ---------- launch ----------

extern "C" void kernel_launch(void* const* d_in, const int* in_sizes, int n_in,
                              void* d_out, int out_size, void* d_ws, size_t ws_size,
                              hipStream_t stream) {
    (void)in_sizes; (void)n_in; (void)out_size; (void)ws_size;

    const float* X       = (const float*)d_in[0];
    const float* W_ampa  = (const float*)d_in[1];
    const float* W_shunt = (const float*)d_in[2];
    const float* Imem    = (const float*)d_in[3];
    const float* Iampa   = (const float*)d_in[4];
    const float* Ishunt  = (const float*)d_in[5];
    const float* Refr    = (const float*)d_in[6];
    const float* pIdc    = (const float*)d_in[7];
    const float* pIwa    = (const float*)d_in[8];
    const float* pIws    = (const float*)d_in[9];
    const float* pAlpha  = (const float*)d_in[10];
    const float* pBeta   = (const float*)d_in[11];

    unsigned short* Xb  = (unsigned short*)d_ws;                 // 16 MiB
    unsigned short* Wab = Xb  + (size_t)B_DIM * K_DIM;           // 8 MiB
    unsigned short* Wsb = Wab + (size_t)N_DIM * K_DIM;           // 8 MiB

    // host-computed double constants, cast to fp32 exactly like the reference
    const float i0pow   = (float)std::pow(5e-13, 1.0 / 1.705);   // I0^(1/(k+1))
    const float kexp    = (float)(0.705 / 1.705);                // k/(k+1)
    const float tau_mem = (float)(0.025 / 0.705 * 3.0);
    const float tau_syn = (float)(0.025 / 0.705 * 2.0);

    cast_x_kernel<<<dim3((B_DIM * K_DIM) / (256 * 8)), dim3(256), 0, stream>>>(X, Xb);
    cast_w_kernel<<<dim3((N_DIM * K_DIM) / (256 * 8)), dim3(256), 0, stream>>>(
        W_ampa, W_shunt, Wab, Wsb);

    dpi_fused_kernel<<<dim3(B_DIM / BM, N_DIM / BN), dim3(256), 0, stream>>>(
        Xb, Wab, Wsb, Imem, Iampa, Ishunt, Refr,
        pIdc, pIwa, pIws, pAlpha, pBeta,
        (float*)d_out, i0pow, kexp, tau_mem, tau_syn);
}

// Round 2
// 369.261 us; speedup vs baseline: 2.0796x; 2.0796x over previous
//
#include <hip/hip_runtime.h>
#include <cmath>

#ifndef __has_builtin
#define __has_builtin(x) 0
#endif

#define B_DIM 4096
#define K_DIM 2048
#define N_DIM 2048

#define BM 128
#define BN 128
#define BK 64

typedef __attribute__((ext_vector_type(4))) float f32x4;
typedef __attribute__((ext_vector_type(8))) short bf16x8;
typedef __attribute__((ext_vector_type(8))) unsigned short u16x8;

// ---------- helpers ----------

__device__ __forceinline__ unsigned short f2bf(float f) {
    unsigned int u = __float_as_uint(f);
    u += 0x7fffu + ((u >> 16) & 1u);   // RNE; values here are small exact ints, no NaN
    return (unsigned short)(u >> 16);
}

__device__ __forceinline__ void gl2lds16(const void* g, void* l) {
#if __has_builtin(__builtin_amdgcn_global_load_lds)
    __builtin_amdgcn_global_load_lds((__attribute__((address_space(1))) void*)g,
                                     (__attribute__((address_space(3))) void*)l,
                                     16, 0, 0);
#else
    *(uint4*)l = *(const uint4*)g;
#endif
}

// ---------- prep: fp32 -> bf16 casts ----------

__global__ void cast_x_kernel(const float* __restrict__ X,
                              unsigned short* __restrict__ Xb) {
    size_t i = ((size_t)blockIdx.x * 256 + threadIdx.x) * 8;
    f32x4 a = *(const f32x4*)(X + i);
    f32x4 b = *(const f32x4*)(X + i + 4);
    u16x8 o;
    o[0] = f2bf(a[0]); o[1] = f2bf(a[1]); o[2] = f2bf(a[2]); o[3] = f2bf(a[3]);
    o[4] = f2bf(b[0]); o[5] = f2bf(b[1]); o[6] = f2bf(b[2]); o[7] = f2bf(b[3]);
    *(u16x8*)(Xb + i) = o;
}

__global__ void cast_w_kernel(const float* __restrict__ Wa,
                              const float* __restrict__ Ws,
                              unsigned short* __restrict__ Wab,
                              unsigned short* __restrict__ Wsb) {
    size_t i = ((size_t)blockIdx.x * 256 + threadIdx.x) * 8;
    f32x4 a0 = *(const f32x4*)(Wa + i);
    f32x4 a1 = *(const f32x4*)(Wa + i + 4);
    f32x4 s0 = *(const f32x4*)(Ws + i);
    f32x4 s1 = *(const f32x4*)(Ws + i + 4);
    u16x8 oa, os;
#pragma unroll
    for (int j = 0; j < 4; j++) {
        oa[j]     = f2bf(rintf(a0[j]));  // ste_round fwd = round-half-even
        oa[j + 4] = f2bf(rintf(a1[j]));
        os[j]     = f2bf(rintf(s0[j]));
        os[j + 4] = f2bf(rintf(s1[j]));
    }
    *(u16x8*)(Wab + i) = oa;
    *(u16x8*)(Wsb + i) = os;
}

// ---------- fused dual-GEMM + DPI neuron update ----------
// 128x128 tile, BK=64, 4 waves 2x2, each wave 64x64 via 4x4 mfma_f32_16x16x32_bf16
// per GEMM. Staging uses global_load_lds with XOR chunk swizzle (conflict-free
// ds_read_b128). Epilogue transposes accumulators through LDS so all global
// reads/writes are row-contiguous float4 (512B runs per row).

#define RS 132   // LDS float row stride for epilogue (128 + 4 pad)

__global__ __launch_bounds__(256, 2)
void dpi_fused_kernel(const unsigned short* __restrict__ Xb,
                      const unsigned short* __restrict__ Wab,
                      const unsigned short* __restrict__ Wsb,
                      const float* __restrict__ gImem,
                      const float* __restrict__ gIampa,
                      const float* __restrict__ gIshunt,
                      const float* __restrict__ gRefr,
                      const float* __restrict__ pIdc,
                      const float* __restrict__ pIwa,
                      const float* __restrict__ pIws,
                      const float* __restrict__ pAlpha,
                      const float* __restrict__ pBeta,
                      float* __restrict__ out,
                      float i0pow, float kexp, float tau_mem, float inv_tau_syn)
{
    __shared__ __align__(16) unsigned char smem[49152];
    unsigned short* sA  = (unsigned short*)smem;             // 16 KB
    unsigned short* sWa = (unsigned short*)(smem + 16384);   // 16 KB
    unsigned short* sWs = (unsigned short*)(smem + 32768);   // 16 KB
    float* na_buf = (float*)smem;                            // 32*RS*4 = 16896 B
    float* ns_buf = (float*)(smem + 16896);                  // 16896 B

    const int tid  = threadIdx.x;
    const int lane = tid & 63;
    const int wave = tid >> 6;

    // XCD-aware swizzle: 8 XCDs, each gets an 8x8 block region (1024x1024 elems)
    const int lin = blockIdx.x;                 // 0..511
    const int xcd = lin & 7;
    const int loc = lin >> 3;                   // 0..63
    const int mb  = (xcd & 3) * 8 + (loc & 7);  // 0..31
    const int nb  = (xcd >> 2) * 8 + (loc >> 3);// 0..15
    const int m0  = mb * BM;
    const int n0  = nb * BN;

    const int wm = (wave & 1) * 64;
    const int wn = (wave >> 1) * 64;

    f32x4 accA[4][4], accS[4][4];
#pragma unroll
    for (int i = 0; i < 4; i++)
#pragma unroll
        for (int j = 0; j < 4; j++) { accA[i][j] = (f32x4)0.0f; accS[i][j] = (f32x4)0.0f; }

    const int frow = lane & 15;           // m (or n) within a 16-frag
    const int kq   = lane >> 4;           // 0..3 -> k sub-offset kq*8
    const int swzr = frow & 7;            // row part of the XOR swizzle

    for (int k0 = 0; k0 < K_DIM; k0 += BK) {
        // stage 3 tiles of 128x64 bf16 (16KB each) = 1024 16B chunks each.
        // LDS dst is forced contiguous (base + lane*16); we XOR-swizzle the
        // GLOBAL source chunk so that row r's chunk j lands at slot j^(r&7).
#pragma unroll
        for (int j = 0; j < 4; j++) {
            int c    = j * 256 + tid;          // LDS chunk 0..1023
            int row  = c >> 3;
            int jsrc = (c & 7) ^ (row & 7);    // source 16B chunk within row
            size_t goffA = (size_t)(m0 + row) * K_DIM + k0 + jsrc * 8;
            size_t goffW = (size_t)(n0 + row) * K_DIM + k0 + jsrc * 8;
            gl2lds16(Xb  + goffA, sA  + c * 8);
            gl2lds16(Wab + goffW, sWa + c * 8);
            gl2lds16(Wsb + goffW, sWs + c * 8);
        }
        __syncthreads();

#pragma unroll
        for (int kk = 0; kk < 2; kk++) {
            const int jb = kk * 4 + kq;        // 16B chunk index of this lane's k
            bf16x8 af[4], ba[4], bs[4];
#pragma unroll
            for (int mi = 0; mi < 4; mi++) {
                const int rA = wm + mi * 16 + frow;
                af[mi] = *(const bf16x8*)(sA + rA * 64 + ((jb ^ swzr) * 8));
            }
#pragma unroll
            for (int ni = 0; ni < 4; ni++) {
                const int rB = wn + ni * 16 + frow;
                const int o  = rB * 64 + ((jb ^ swzr) * 8);
                ba[ni] = *(const bf16x8*)(sWa + o);
                bs[ni] = *(const bf16x8*)(sWs + o);
            }
#pragma unroll
            for (int mi = 0; mi < 4; mi++)
#pragma unroll
                for (int ni = 0; ni < 4; ni++) {
                    accA[mi][ni] = __builtin_amdgcn_mfma_f32_16x16x32_bf16(af[mi], ba[ni], accA[mi][ni], 0, 0, 0);
                    accS[mi][ni] = __builtin_amdgcn_mfma_f32_16x16x32_bf16(af[mi], bs[ni], accS[mi][ni], 0, 0, 0);
                }
        }
        __syncthreads();
    }

    // ---- epilogue: transpose through LDS, then contiguous float4 I/O ----
    const float idc   = *pIdc;
    const float iwa   = *pIwa;
    const float iws   = *pIws;
    const float alpha = *pAlpha;
    const float beta  = *pBeta;

    const size_t plane = (size_t)B_DIM * N_DIM;
    float* __restrict__ oSpike = out;
    float* __restrict__ oImem  = out + plane;
    float* __restrict__ oIampa = out + 2 * plane;
    float* __restrict__ oIsh   = out + 3 * plane;
    float* __restrict__ oRefr  = out + 4 * plane;

    const int rowgroup = wm >> 6;          // 0 or 1
    const int quad4    = (lane >> 4) << 2; // 0,4,8,12
    const int cseg     = (tid & 31) * 4;   // float4 column
    const int rgrp     = tid >> 5;         // 0..7 -> rows rgrp*4..+3

#pragma unroll
    for (int s = 0; s < 4; s++) {          // s == mi: 32 rows of the tile per step
        // scatter fragments into LDS (C/D layout: col=lane&15, row=quad*4+r)
#pragma unroll
        for (int ni = 0; ni < 4; ni++) {
            const int lcol = wn + ni * 16 + (lane & 15);
#pragma unroll
            for (int r = 0; r < 4; r++) {
                const int lrow = rowgroup * 16 + quad4 + r;
                na_buf[lrow * RS + lcol] = accA[s][ni][r];
                ns_buf[lrow * RS + lcol] = accS[s][ni][r];
            }
        }
        __syncthreads();

        // contiguous compute + store: each thread owns 4 rows x 1 float4
#pragma unroll
        for (int q = 0; q < 4; q++) {
            const int lrow = rgrp * 4 + q;
            const int grow = m0 + (lrow >> 4) * 64 + s * 16 + (lrow & 15);
            const size_t idx = (size_t)grow * N_DIM + n0 + cseg;

            const f32x4 na4 = *(const f32x4*)(na_buf + lrow * RS + cseg);
            const f32x4 ns4 = *(const f32x4*)(ns_buf + lrow * RS + cseg);
            const f32x4 im4 = *(const f32x4*)(gImem   + idx);
            const f32x4 ia4 = *(const f32x4*)(gIampa  + idx);
            const f32x4 is4 = *(const f32x4*)(gIshunt + idx);
            const f32x4 rf4 = *(const f32x4*)(gRefr   + idx);

            f32x4 sp_o, im_o, ia_o, is_o, rf_o;
#pragma unroll
            for (int e = 0; e < 4; e++) {
                const float na  = na4[e];
                const float ns  = ns4[e];
                const float im  = im4[e];
                const float ia  = ia4[e];
                const float ish = is4[e];
                const float rf  = rf4[e];

                const float dIampa  = -ia * inv_tau_syn;
                const float ia2     = ia + iwa * na;        // IGAIN_AMPA/ITAU_AMPA = 1
                const float dIshunt = -ish * inv_tau_syn;   // TAU_SHUNT == TAU_AMPA
                const float ish2    = ish + iws * ns;

                float Iin = idc + ia2 + 5e-13f - ish2;      // Inmda = I0
                Iin = (rf <= 0.0f) ? Iin : 0.0f;
                Iin = fmaxf(Iin, 5e-13f);

                // 1+exp(-1e-12*(im-1e-12)): |arg| < 1e-21 -> exp == 1.0f exactly
                // in fp32, denominator == 2.0f. powf via v_log/v_exp.
                const float ifb = i0pow *
                    __builtin_amdgcn_exp2f(kexp * __builtin_amdgcn_logf(im)) * 0.5f;
                const float fimem = ifb * 1e12f * (im + 1e-12f);
                const float dImem = (alpha * ((Iin - 1e-12f) - 5e-13f) - beta * im + fimem)
                                    / (tau_mem * (1.0f + 1e-12f / im));
                float im2 = fmaxf(im + dImem * 0.001f, 5e-13f);

                float ia3 = fmaxf(ia2 + dIampa * 0.001f, 5e-13f);
                ia3       = fmaxf(ia3 + dIshunt * 0.001f, 5e-13f);  // faithful to ref bug

                const float spike = (im2 - 1e-12f > 0.0f) ? 1.0f : 0.0f;
                im2 = (spike > 0.0f) ? 5e-13f : im2;
                float rf2 = fmaxf(rf - 0.001f, 0.0f);
                rf2 = (spike > 0.0f) ? 0.0f : rf2;          // REFP = 0

                sp_o[e] = spike; im_o[e] = im2; ia_o[e] = ia3;
                is_o[e] = ish2;  rf_o[e] = rf2;
            }

            *(f32x4*)(oSpike + idx) = sp_o;
            *(f32x4*)(oImem  + idx) = im_o;
            *(f32x4*)(oIampa + idx) = ia_o;
            *(f32x4*)(oIsh   + idx) = is_o;
            *(f32x4*)(oRefr  + idx) = rf_o;
        }
        __syncthreads();
    }
}

// ---------- launch ----------

extern "C" void kernel_launch(void* const* d_in, const int* in_sizes, int n_in,
                              void* d_out, int out_size, void* d_ws, size_t ws_size,
                              hipStream_t stream) {
    (void)in_sizes; (void)n_in; (void)out_size; (void)ws_size;

    const float* X       = (const float*)d_in[0];
    const float* W_ampa  = (const float*)d_in[1];
    const float* W_shunt = (const float*)d_in[2];
    const float* Imem    = (const float*)d_in[3];
    const float* Iampa   = (const float*)d_in[4];
    const float* Ishunt  = (const float*)d_in[5];
    const float* Refr    = (const float*)d_in[6];
    const float* pIdc    = (const float*)d_in[7];
    const float* pIwa    = (const float*)d_in[8];
    const float* pIws    = (const float*)d_in[9];
    const float* pAlpha  = (const float*)d_in[10];
    const float* pBeta   = (const float*)d_in[11];

    unsigned short* Xb  = (unsigned short*)d_ws;                 // 16 MiB
    unsigned short* Wab = Xb  + (size_t)B_DIM * K_DIM;           // 8 MiB
    unsigned short* Wsb = Wab + (size_t)N_DIM * K_DIM;           // 8 MiB

    const float i0pow       = (float)std::pow(5e-13, 1.0 / 1.705);   // I0^(1/(k+1))
    const float kexp        = (float)(0.705 / 1.705);                // k/(k+1)
    const float tau_mem     = (float)(0.025 / 0.705 * 3.0);
    const float inv_tau_syn = (float)(1.0 / (0.025 / 0.705 * 2.0));

    cast_x_kernel<<<dim3((B_DIM * K_DIM) / (256 * 8)), dim3(256), 0, stream>>>(X, Xb);
    cast_w_kernel<<<dim3((N_DIM * K_DIM) / (256 * 8)), dim3(256), 0, stream>>>(
        W_ampa, W_shunt, Wab, Wsb);

    dpi_fused_kernel<<<dim3(512), dim3(256), 0, stream>>>(
        Xb, Wab, Wsb, Imem, Iampa, Ishunt, Refr,
        pIdc, pIwa, pIws, pAlpha, pBeta,
        (float*)d_out, i0pow, kexp, tau_mem, inv_tau_syn);
}